// Round 9
// baseline (676.155 us; speedup 1.0000x reference)
//
#include <hip/hip_runtime.h>
#include <hip/hip_bf16.h>

#define N_NODES 50000
#define N_EDGES 600000
#define D 128
#define LN_EPS 1e-5f

typedef float f32x4 __attribute__((ext_vector_type(4)));
typedef int   i32x4 __attribute__((ext_vector_type(4)));
typedef short s16x8 __attribute__((ext_vector_type(8)));   // 8 bf16 = 4 VGPRs

// ---- workspace byte offsets (all 64B-aligned) ----
#define W1P_OFF     0u          // 384x128 bf16 packed frags (98304 B)
#define W2P_OFF     98304u      // 128x128 bf16 (32768 B)
#define NW1P_OFF    131072u     // 256x128 bf16 (65536 B)
#define NW2P_OFF    196608u     // 128x128 bf16 (32768 B)
#define SEGKEY_OFF  229376u     // 50000 u32
#define SEGSUM_OFF  429440u     // 50000 f32
#define LOGITS_OFF  629504u     // 600000 f32
#define EX_OFF      3029504u    // 600000 f32
#define AGG_OFF     5429504u    // 50000x128 f32 (25.6 MB)
#define RAW_OFF     31029504u   // 600000x128 bf16 raw new_ef (153.6 MB), optional
#define WS_NEED_RAW (RAW_OFF + (size_t)N_EDGES * D * 2)    // 184629504 B

static __device__ __forceinline__ unsigned short f2bf(float f) {
    unsigned int u = __float_as_uint(f);
    u = (u + 0x7FFFu + ((u >> 16) & 1u)) >> 16;   // RNE f32->bf16
    return (unsigned short)u;
}
static __device__ __forceinline__ float bf2f(unsigned short h) {
    unsigned int u = ((unsigned int)h) << 16;
    return __uint_as_float(u);
}
// pack two f32 -> bf16x2 in one int (compiler folds to v_cvt_pk_bf16_f32)
static __device__ __forceinline__ int pkbf2(float a, float b) {
    union { __hip_bfloat16 h[2]; int i; } u;
    u.h[0] = __float2bfloat16(a);
    u.h[1] = __float2bfloat16(b);
    return u.i;
}
union frag_u { i32x4 i; s16x8 s; };
// order-preserving float<->uint key for atomicMax-based segment max
static __device__ __forceinline__ unsigned int fkey(float f) {
    unsigned int u = __float_as_uint(f);
    return (u & 0x80000000u) ? ~u : (u | 0x80000000u);
}
static __device__ __forceinline__ float unkey(unsigned int k) {
    unsigned int u = (k & 0x80000000u) ? (k & 0x7FFFFFFFu) : ~k;
    return __uint_as_float(u);
}
// D = A(16x32)*B(32x16)+C. A: lane row=l&15, k=8*(l>>4)+e. B: col=l&15, k=8*(l>>4)+e.
// C/D: col=lane&15, row=(lane>>4)*4+reg  [m89]
static __device__ __forceinline__ f32x4 mfma_bf16(s16x8 a, s16x8 b, f32x4 c) {
    return __builtin_amdgcn_mfma_f32_16x16x32_bf16(a, b, c, 0, 0, 0);
}

// ---------------- init: zero accumulators, pack weights into MFMA frag order ----------------
__global__ void k_init(const float* __restrict__ eW1, const float* __restrict__ eW2,
                       const float* __restrict__ nW1, const float* __restrict__ nW2,
                       char* __restrict__ ws) {
    int idx = blockIdx.x * 256 + threadIdx.x;
    if (idx < N_NODES * D) ((float*)(ws + AGG_OFF))[idx] = 0.0f;
    if (idx < N_NODES) {
        ((unsigned int*)(ws + SEGKEY_OFF))[idx] = 0u;   // key 0 < key(any float)
        ((float*)(ws + SEGSUM_OFF))[idx] = 0.0f;
    }
    // packed layout: bf16 i = ((ks*8+ct)*64+lane)*8+e ; k=ks*32+(lane>>4)*8+e ; j=ct*16+(lane&15)
    int e = idx & 7, lane = (idx >> 3) & 63, ct = (idx >> 9) & 7, ks = idx >> 12;
    int k = ks * 32 + (lane >> 4) * 8 + e;
    int j = ct * 16 + (lane & 15);
    if (idx < 12 * 4096) ((unsigned short*)(ws + W1P_OFF))[idx]  = f2bf(eW1[k * 128 + j]);
    if (idx < 4 * 4096)  ((unsigned short*)(ws + W2P_OFF))[idx]  = f2bf(eW2[k * 128 + j]);
    if (idx < 8 * 4096)  ((unsigned short*)(ws + NW1P_OFF))[idx] = f2bf(nW1[k * 128 + j]);
    if (idx < 4 * 4096)  ((unsigned short*)(ws + NW2P_OFF))[idx] = f2bf(nW2[k * 128 + j]);
}

// ---------------- edge MLP + LN + residual + logits + segment-max ----------------
// One-tile per wave (proven mapping) + double-buffered LDS B slices (R8).
// R9: conflict-free staging write pattern ([tid],[256+tid]); optional bf16 raw store.
template <int STORE_RAW>
__global__ __launch_bounds__(256, 4) void k_edge(
    const float* __restrict__ nf, const float* __restrict__ ef,
    const int* __restrict__ snd, const int* __restrict__ rcv,
    const i32x4* __restrict__ B1, const i32x4* __restrict__ B2,
    const float* __restrict__ b1, const float* __restrict__ b2,
    const float* __restrict__ g, const float* __restrict__ beta,
    const float* __restrict__ aW, const float* __restrict__ ab,
    float* __restrict__ out_ef, float* __restrict__ logits,
    unsigned int* __restrict__ segkey, unsigned short* __restrict__ rawbuf)
{
    __shared__ __align__(16) char  hbuf[64 * 128 * 2];   // 16 KB, wave-private rows
    __shared__ __align__(16) i32x4 bstage[2][512];       // 2 x 8 KB B slices
    const int tid = threadIdx.x, lane = tid & 63, rt = tid >> 6;
    const int j0 = lane & 15, hi = lane >> 4;

    // this lane's A-row: edge index for rows of wave rt
    const long eA = (long)blockIdx.x * 64 + rt * 16 + j0;
    const int sA = snd[eA], rA = rcv[eA];
    const float* __restrict__ prowS = nf + (size_t)sA * D;
    const float* __restrict__ prowR = nf + (size_t)rA * D;
    const float* __restrict__ prowE = ef + (size_t)eA * D;

    // prologue: stage slice 0 (B1 ks=0); 16B-stride writes = conflict-free
    bstage[0][tid]       = B1[tid];
    bstage[0][256 + tid] = B1[256 + tid];
    __syncthreads();

    // GEMM1: (64x384)@(384x128); slices s=0..11
    f32x4 acc[8];
    #pragma unroll
    for (int ct = 0; ct < 8; ++ct) acc[ct] = (f32x4){0.f, 0.f, 0.f, 0.f};
    for (int s = 0; s < 12; ++s) {
        const int cur = s & 1, nxt = cur ^ 1;
        // stage slice s+1 (B1 if s+1<12 else B2 slice 0)
        const i32x4* src = (s + 1 < 12) ? (B1 + (s + 1) * 512) : B2;
        i32x4 t0 = src[tid], t1 = src[256 + tid];
        bstage[nxt][tid]       = t0;
        bstage[nxt][256 + tid] = t1;
        // A frag straight from global
        const float* p = (s < 4 ? prowS : (s < 8 ? prowR : prowE)) + (s & 3) * 32 + hi * 8;
        float4 f0 = *(const float4*)p;
        float4 f1 = *(const float4*)(p + 4);
        frag_u a;
        a.i[0] = pkbf2(f0.x, f0.y); a.i[1] = pkbf2(f0.z, f0.w);
        a.i[2] = pkbf2(f1.x, f1.y); a.i[3] = pkbf2(f1.z, f1.w);
        #pragma unroll
        for (int ct = 0; ct < 8; ++ct) {
            frag_u b; b.i = bstage[cur][ct * 64 + lane];
            acc[ct] = mfma_bf16(a.s, b.s, acc[ct]);
        }
        __syncthreads();   // staged slice complete + reads of cur done
    }

    // h = relu(y1+b1) -> wave-private LDS rows [16rt,16rt+16), XOR-swizzled
    #pragma unroll
    for (int ct = 0; ct < 8; ++ct) {
        float bb = b1[ct * 16 + j0];
        #pragma unroll
        for (int rg = 0; rg < 4; ++rg) {
            int row = rt * 16 + hi * 4 + rg;
            float y = fmaxf(acc[ct][rg] + bb, 0.0f);
            int addr = (row * 256 + (ct * 16 + j0) * 2) ^ ((row & 7) << 4);
            *(__hip_bfloat16*)(hbuf + addr) = __float2bfloat16(y);
        }
    }
    asm volatile("" ::: "memory");   // pin h store->load order (same-wave rows)

    // GEMM2: (64x128)@(128x128); slices 12..15, REUSE acc
    #pragma unroll
    for (int ct = 0; ct < 8; ++ct) acc[ct] = (f32x4){0.f, 0.f, 0.f, 0.f};
    {
        const int arow = rt * 16 + j0;
        for (int s2 = 0; s2 < 4; ++s2) {
            const int cur = (12 + s2) & 1, nxt = cur ^ 1;
            if (s2 < 3) {
                const i32x4* src = B2 + (s2 + 1) * 512;
                i32x4 t0 = src[tid], t1 = src[256 + tid];
                bstage[nxt][tid]       = t0;
                bstage[nxt][256 + tid] = t1;
            }
            int addr = (arow * 256 + (s2 * 32 + hi * 8) * 2) ^ ((arow & 7) << 4);
            frag_u a;
            a.i = *(const i32x4*)(hbuf + addr);
            #pragma unroll
            for (int ct = 0; ct < 8; ++ct) {
                frag_u b; b.i = bstage[cur][ct * 64 + lane];
                acc[ct] = mfma_bf16(a.s, b.s, acc[ct]);
            }
            if (s2 < 3) __syncthreads();
        }
    }

    // LayerNorm + residual write + attention logit + segment-max
    float b2v[8], gv[8], bv[8], awv[8];
    #pragma unroll
    for (int ct = 0; ct < 8; ++ct) {
        int c = ct * 16 + j0;
        b2v[ct] = b2[c]; gv[ct] = g[c]; bv[ct] = beta[c]; awv[ct] = aW[c];
    }
    float abv = ab[0];
    #pragma unroll
    for (int rg = 0; rg < 4; ++rg) {
        int row = rt * 16 + hi * 4 + rg;
        long e = (long)blockIdx.x * 64 + row;
        float y[8]; float s = 0.f, sq = 0.f;
        #pragma unroll
        for (int ct = 0; ct < 8; ++ct) {
            y[ct] = acc[ct][rg] + b2v[ct];
            s += y[ct]; sq += y[ct] * y[ct];
        }
        #pragma unroll
        for (int m = 1; m <= 8; m <<= 1) { s += __shfl_xor(s, m); sq += __shfl_xor(sq, m); }
        float mu = s * (1.0f / 128.0f);
        float var = sq * (1.0f / 128.0f) - mu * mu;
        float rs = rsqrtf(var + LN_EPS);
        const float* efr = ef + (size_t)e * D;
        float* outr = out_ef + (size_t)e * D;
        unsigned short* rawr = STORE_RAW ? (rawbuf + (size_t)e * D) : nullptr;
        float lg = 0.f;
        #pragma unroll
        for (int ct = 0; ct < 8; ++ct) {
            int c = ct * 16 + j0;
            float o = (y[ct] - mu) * rs * gv[ct] + bv[ct];   // new_ef_raw
            outr[c] = o + efr[c];                            // residual output
            if (STORE_RAW) rawr[c] = f2bf(o);                // bf16 raw for scatter
            lg += o * awv[ct];
        }
        #pragma unroll
        for (int m = 1; m <= 8; m <<= 1) lg += __shfl_xor(lg, m);
        if (j0 == 0) {
            float L = lg + abv;
            L = (L >= 0.f) ? L : 0.2f * L;                   // leaky_relu 0.2
            logits[e] = L;
            atomicMax(&segkey[rcv[e]], fkey(L));
        }
    }
}

// ---------------- ex = exp(logit - segmax[r]); segsum += ex ----------------
__global__ void k_exps(const float* __restrict__ logits, const int* __restrict__ rcv,
                       const unsigned int* __restrict__ segkey,
                       float* __restrict__ ex, float* __restrict__ segsum)
{
    int e = blockIdx.x * 256 + threadIdx.x;
    if (e >= N_EDGES) return;
    int r = rcv[e];
    float v = __expf(logits[e] - unkey(segkey[r]));
    ex[e] = v;
    unsafeAtomicAdd(&segsum[r], v);
}

// ---------------- agg[r] += raw * att — raw from bf16 buffer (no out_ef/ef re-read) ----------------
__global__ void k_scatter_raw(const unsigned short* __restrict__ raw,
                              const int* __restrict__ rcv, const float* __restrict__ ex,
                              const float* __restrict__ segsum, float* __restrict__ agg)
{
    long idx = (long)blockIdx.x * 256 + threadIdx.x;   // N_EDGES*D threads exactly
    int e = (int)(idx >> 7);
    int c = (int)(idx & 127);
    int r = rcv[e];
    float att = ex[e] / segsum[r];
    unsafeAtomicAdd(&agg[(size_t)r * D + c], bf2f(raw[idx]) * att);
}

// ---------------- fallback scatter (R6-proven) when ws too small for raw ----------------
__global__ void k_scatter(const float* __restrict__ out_ef, const float* __restrict__ ef,
                          const int* __restrict__ rcv, const float* __restrict__ ex,
                          const float* __restrict__ segsum, float* __restrict__ agg)
{
    long idx = (long)blockIdx.x * 256 + threadIdx.x;
    int e = (int)(idx >> 7);
    int c = (int)(idx & 127);
    int r = rcv[e];
    float att = ex[e] / segsum[r];
    float raw = out_ef[idx] - ef[idx];
    unsafeAtomicAdd(&agg[(size_t)r * D + c], raw * att);
}

// ---------------- node MLP + LN + residual (barrier-free template, proven) ----------------
__global__ __launch_bounds__(256, 4) void k_node(
    const float* __restrict__ nf, const float* __restrict__ agg,
    const s16x8* __restrict__ B1, const s16x8* __restrict__ B2,
    const float* __restrict__ b1, const float* __restrict__ b2,
    const float* __restrict__ g, const float* __restrict__ beta,
    float* __restrict__ out_nf)
{
    __shared__ __align__(16) char hbuf[64 * 128 * 2];   // 16 KB
    const int tid = threadIdx.x, lane = tid & 63, rt = tid >> 6;
    const int j0 = lane & 15, hi = lane >> 4;

    long nA = (long)blockIdx.x * 64 + rt * 16 + j0;
    if (nA >= N_NODES) nA = 0;                           // pad rows: safe reads, writes guarded
    const float* __restrict__ prowN = nf  + (size_t)nA * D;
    const float* __restrict__ prowA = agg + (size_t)nA * D;

    f32x4 acc[8];
    #pragma unroll
    for (int ct = 0; ct < 8; ++ct) acc[ct] = (f32x4){0.f, 0.f, 0.f, 0.f};
    #pragma unroll
    for (int ks = 0; ks < 8; ++ks) {
        const float* p = (ks < 4 ? prowN : prowA) + (ks & 3) * 32 + hi * 8;
        float4 f0 = *(const float4*)p;
        float4 f1 = *(const float4*)(p + 4);
        frag_u a;
        a.i[0] = pkbf2(f0.x, f0.y); a.i[1] = pkbf2(f0.z, f0.w);
        a.i[2] = pkbf2(f1.x, f1.y); a.i[3] = pkbf2(f1.z, f1.w);
        #pragma unroll
        for (int ct = 0; ct < 8; ++ct)
            acc[ct] = mfma_bf16(a.s, B1[(ks * 8 + ct) * 64 + lane], acc[ct]);
    }

    #pragma unroll
    for (int ct = 0; ct < 8; ++ct) {
        float bb = b1[ct * 16 + j0];
        #pragma unroll
        for (int rg = 0; rg < 4; ++rg) {
            int row = rt * 16 + hi * 4 + rg;
            float y = fmaxf(acc[ct][rg] + bb, 0.0f);
            int addr = (row * 256 + (ct * 16 + j0) * 2) ^ ((row & 7) << 4);
            *(__hip_bfloat16*)(hbuf + addr) = __float2bfloat16(y);
        }
    }
    asm volatile("" ::: "memory");

    // GEMM2 — reuse acc
    #pragma unroll
    for (int ct = 0; ct < 8; ++ct) acc[ct] = (f32x4){0.f, 0.f, 0.f, 0.f};
    {
        int arow = rt * 16 + j0;
        #pragma unroll
        for (int ks = 0; ks < 4; ++ks) {
            int addr = (arow * 256 + (ks * 32 + hi * 8) * 2) ^ ((arow & 7) << 4);
            frag_u a;
            a.i = *(const i32x4*)(hbuf + addr);
            #pragma unroll
            for (int ct = 0; ct < 8; ++ct)
                acc[ct] = mfma_bf16(a.s, B2[(ks * 8 + ct) * 64 + lane], acc[ct]);
        }
    }

    float b2v[8], gv[8], bv[8];
    #pragma unroll
    for (int ct = 0; ct < 8; ++ct) {
        int c = ct * 16 + j0;
        b2v[ct] = b2[c]; gv[ct] = g[c]; bv[ct] = beta[c];
    }
    #pragma unroll
    for (int rg = 0; rg < 4; ++rg) {
        int row = rt * 16 + hi * 4 + rg;
        long n = (long)blockIdx.x * 64 + row;
        float y[8]; float s = 0.f, sq = 0.f;
        #pragma unroll
        for (int ct = 0; ct < 8; ++ct) {
            y[ct] = acc[ct][rg] + b2v[ct];
            s += y[ct]; sq += y[ct] * y[ct];
        }
        #pragma unroll
        for (int m = 1; m <= 8; m <<= 1) { s += __shfl_xor(s, m); sq += __shfl_xor(sq, m); }
        float mu = s * (1.0f / 128.0f);
        float var = sq * (1.0f / 128.0f) - mu * mu;
        float rs = rsqrtf(var + LN_EPS);
        if (n < N_NODES) {
            const float* nfr = nf + (size_t)n * D;
            float* outr = out_nf + (size_t)n * D;
            #pragma unroll
            for (int ct = 0; ct < 8; ++ct) {
                int c = ct * 16 + j0;
                float o = (y[ct] - mu) * rs * gv[ct] + bv[ct];
                outr[c] = o + nfr[c];                        // + node residual
            }
        }
    }
}

extern "C" void kernel_launch(void* const* d_in, const int* in_sizes, int n_in,
                              void* d_out, int out_size, void* d_ws, size_t ws_size,
                              hipStream_t stream)
{
    (void)in_sizes; (void)n_in; (void)out_size;
    const float* nf    = (const float*)d_in[0];
    const float* ef    = (const float*)d_in[1];
    const int*   snd   = (const int*)d_in[2];
    const int*   rcv   = (const int*)d_in[3];
    const float* eW1   = (const float*)d_in[4];
    const float* eb1   = (const float*)d_in[5];
    const float* eW2   = (const float*)d_in[6];
    const float* eb2   = (const float*)d_in[7];
    const float* eg    = (const float*)d_in[8];
    const float* ebeta = (const float*)d_in[9];
    const float* nW1   = (const float*)d_in[10];
    const float* nb1   = (const float*)d_in[11];
    const float* nW2   = (const float*)d_in[12];
    const float* nb2   = (const float*)d_in[13];
    const float* ng    = (const float*)d_in[14];
    const float* nbeta = (const float*)d_in[15];
    const float* aW    = (const float*)d_in[16];
    const float* ab    = (const float*)d_in[17];

    float* out_nf = (float*)d_out;
    float* out_ef = out_nf + (size_t)N_NODES * D;
    char*  ws     = (char*)d_ws;

    const bool use_raw = (ws_size >= WS_NEED_RAW);   // constant per-harness -> deterministic

    k_init<<<25000, 256, 0, stream>>>(eW1, eW2, nW1, nW2, ws);

    if (use_raw) {
        k_edge<1><<<N_EDGES / 64, 256, 0, stream>>>(
            nf, ef, snd, rcv,
            (const i32x4*)(ws + W1P_OFF), (const i32x4*)(ws + W2P_OFF),
            eb1, eb2, eg, ebeta, aW, ab,
            out_ef, (float*)(ws + LOGITS_OFF), (unsigned int*)(ws + SEGKEY_OFF),
            (unsigned short*)(ws + RAW_OFF));
    } else {
        k_edge<0><<<N_EDGES / 64, 256, 0, stream>>>(
            nf, ef, snd, rcv,
            (const i32x4*)(ws + W1P_OFF), (const i32x4*)(ws + W2P_OFF),
            eb1, eb2, eg, ebeta, aW, ab,
            out_ef, (float*)(ws + LOGITS_OFF), (unsigned int*)(ws + SEGKEY_OFF),
            nullptr);
    }

    k_exps<<<(N_EDGES + 255) / 256, 256, 0, stream>>>(
        (const float*)(ws + LOGITS_OFF), rcv, (const unsigned int*)(ws + SEGKEY_OFF),
        (float*)(ws + EX_OFF), (float*)(ws + SEGSUM_OFF));

    if (use_raw) {
        k_scatter_raw<<<(int)(((long)N_EDGES * D) / 256), 256, 0, stream>>>(
            (const unsigned short*)(ws + RAW_OFF), rcv, (const float*)(ws + EX_OFF),
            (const float*)(ws + SEGSUM_OFF), (float*)(ws + AGG_OFF));
    } else {
        k_scatter<<<(int)(((long)N_EDGES * D) / 256), 256, 0, stream>>>(
            out_ef, ef, rcv, (const float*)(ws + EX_OFF),
            (const float*)(ws + SEGSUM_OFF), (float*)(ws + AGG_OFF));
    }

    k_node<<<(N_NODES + 63) / 64, 256, 0, stream>>>(
        nf, (const float*)(ws + AGG_OFF),
        (const s16x8*)(ws + NW1P_OFF), (const s16x8*)(ws + NW2P_OFF),
        nb1, nb2, ng, nbeta, out_nf);
}

// Round 10
// 653.587 us; speedup vs baseline: 1.0345x; 1.0345x over previous
//
#include <hip/hip_runtime.h>
#include <hip/hip_bf16.h>

#define N_NODES 50000
#define N_EDGES 600000
#define D 128
#define LN_EPS 1e-5f

typedef float f32x4 __attribute__((ext_vector_type(4)));
typedef int   i32x4 __attribute__((ext_vector_type(4)));
typedef short s16x8 __attribute__((ext_vector_type(8)));   // 8 bf16 = 4 VGPRs

// ---- workspace byte offsets (all 64B-aligned where it matters) ----
#define W1P_OFF     0u          // 384x128 bf16 packed frags (98304 B)
#define W2P_OFF     98304u      // 128x128 bf16 (32768 B)
#define NW1P_OFF    131072u     // 256x128 bf16 (65536 B)
#define NW2P_OFF    196608u     // 128x128 bf16 (32768 B)
#define DEG_OFF     229376u     // 50000 i32   -> 429376
#define ROWPTR_OFF  429440u     // 50001 i32   -> 629444
#define LOGITS_OFF  629504u     // 600000 f32  -> 3029504
#define CURSOR_OFF  3029504u    // 50000 i32   -> 3229504
#define ELIST_OFF   3229504u    // 600000 i32  -> 5629504
#define AGG_OFF     5629504u    // 50000x128 f32 -> 31229504
#define RAW_OFF     31229504u   // 600000x128 bf16 (153.6 MB), optional
#define WS_NEED_RAW (RAW_OFF + (size_t)N_EDGES * D * 2)    // 184829504 B

static __device__ __forceinline__ unsigned short f2bf(float f) {
    unsigned int u = __float_as_uint(f);
    u = (u + 0x7FFFu + ((u >> 16) & 1u)) >> 16;   // RNE f32->bf16
    return (unsigned short)u;
}
static __device__ __forceinline__ float bf2f(unsigned short h) {
    return __uint_as_float(((unsigned int)h) << 16);
}
// pack two f32 -> bf16x2 in one int (compiler folds to v_cvt_pk_bf16_f32)
static __device__ __forceinline__ int pkbf2(float a, float b) {
    union { __hip_bfloat16 h[2]; int i; } u;
    u.h[0] = __float2bfloat16(a);
    u.h[1] = __float2bfloat16(b);
    return u.i;
}
union frag_u { i32x4 i; s16x8 s; };
// D = A(16x32)*B(32x16)+C. A: lane row=l&15, k=8*(l>>4)+e. B: col=l&15, k=8*(l>>4)+e.
// C/D: col=lane&15, row=(lane>>4)*4+reg  [m89]
static __device__ __forceinline__ f32x4 mfma_bf16(s16x8 a, s16x8 b, f32x4 c) {
    return __builtin_amdgcn_mfma_f32_16x16x32_bf16(a, b, c, 0, 0, 0);
}

// ---------------- init: pack weights into MFMA frag order; zero CSR counters ----------------
__global__ void k_init(const float* __restrict__ eW1, const float* __restrict__ eW2,
                       const float* __restrict__ nW1, const float* __restrict__ nW2,
                       char* __restrict__ ws) {
    int idx = blockIdx.x * 256 + threadIdx.x;
    if (idx < N_NODES) {
        ((int*)(ws + DEG_OFF))[idx] = 0;
        ((int*)(ws + CURSOR_OFF))[idx] = 0;
    }
    // packed layout: bf16 i = ((ks*8+ct)*64+lane)*8+e ; k=ks*32+(lane>>4)*8+e ; j=ct*16+(lane&15)
    int e = idx & 7, lane = (idx >> 3) & 63, ct = (idx >> 9) & 7, ks = idx >> 12;
    int k = ks * 32 + (lane >> 4) * 8 + e;
    int j = ct * 16 + (lane & 15);
    if (idx < 12 * 4096) ((unsigned short*)(ws + W1P_OFF))[idx]  = f2bf(eW1[k * 128 + j]);
    if (idx < 4 * 4096)  ((unsigned short*)(ws + W2P_OFF))[idx]  = f2bf(eW2[k * 128 + j]);
    if (idx < 8 * 4096)  ((unsigned short*)(ws + NW1P_OFF))[idx] = f2bf(nW1[k * 128 + j]);
    if (idx < 4 * 4096)  ((unsigned short*)(ws + NW2P_OFF))[idx] = f2bf(nW2[k * 128 + j]);
}

// ---------------- CSR build: count / scan / fill ----------------
__global__ void k_count(const int* __restrict__ rcv, int* __restrict__ deg) {
    int e = blockIdx.x * 256 + threadIdx.x;
    if (e < N_EDGES) atomicAdd(&deg[rcv[e]], 1);
}

__global__ void k_scan(const int* __restrict__ deg, int* __restrict__ rowptr) {
    __shared__ int part[256];
    const int tid = threadIdx.x;
    const int CH = (N_NODES + 255) / 256;           // 196 per thread
    const int base = tid * CH;
    int s = 0;
    for (int i = 0; i < CH; ++i) { int idx = base + i; if (idx < N_NODES) s += deg[idx]; }
    part[tid] = s;
    __syncthreads();
    if (tid == 0) {
        int run = 0;
        for (int j = 0; j < 256; ++j) { int t = part[j]; part[j] = run; run += t; }
        rowptr[N_NODES] = run;                      // = N_EDGES
    }
    __syncthreads();
    int run = part[tid];
    for (int i = 0; i < CH; ++i) {
        int idx = base + i;
        if (idx < N_NODES) { rowptr[idx] = run; run += deg[idx]; }
    }
}

__global__ void k_fill(const int* __restrict__ rcv, const int* __restrict__ rowptr,
                       int* __restrict__ cursor, int* __restrict__ elist) {
    int e = blockIdx.x * 256 + threadIdx.x;
    if (e >= N_EDGES) return;
    int r = rcv[e];
    int slot = atomicAdd(&cursor[r], 1);
    elist[rowptr[r] + slot] = e;
}

// ---------------- edge MLP + LN + residual + logits ----------------
// One-tile per wave (proven mapping) + double-buffered LDS B slices (R8) with
// conflict-free staging (R9). Segment-max removed (k_agg computes it per node).
template <int STORE_RAW>
__global__ __launch_bounds__(256, 4) void k_edge(
    const float* __restrict__ nf, const float* __restrict__ ef,
    const int* __restrict__ snd, const int* __restrict__ rcv,
    const i32x4* __restrict__ B1, const i32x4* __restrict__ B2,
    const float* __restrict__ b1, const float* __restrict__ b2,
    const float* __restrict__ g, const float* __restrict__ beta,
    const float* __restrict__ aW, const float* __restrict__ ab,
    float* __restrict__ out_ef, float* __restrict__ logits,
    unsigned short* __restrict__ rawbuf)
{
    __shared__ __align__(16) char  hbuf[64 * 128 * 2];   // 16 KB, wave-private rows
    __shared__ __align__(16) i32x4 bstage[2][512];       // 2 x 8 KB B slices
    const int tid = threadIdx.x, lane = tid & 63, rt = tid >> 6;
    const int j0 = lane & 15, hi = lane >> 4;

    const long eA = (long)blockIdx.x * 64 + rt * 16 + j0;
    const int sA = snd[eA], rA = rcv[eA];
    const float* __restrict__ prowS = nf + (size_t)sA * D;
    const float* __restrict__ prowR = nf + (size_t)rA * D;
    const float* __restrict__ prowE = ef + (size_t)eA * D;

    // prologue: stage slice 0 (B1 ks=0); 16B-stride writes = conflict-free
    bstage[0][tid]       = B1[tid];
    bstage[0][256 + tid] = B1[256 + tid];
    __syncthreads();

    // GEMM1: (64x384)@(384x128); slices s=0..11
    f32x4 acc[8];
    #pragma unroll
    for (int ct = 0; ct < 8; ++ct) acc[ct] = (f32x4){0.f, 0.f, 0.f, 0.f};
    for (int s = 0; s < 12; ++s) {
        const int cur = s & 1, nxt = cur ^ 1;
        const i32x4* src = (s + 1 < 12) ? (B1 + (s + 1) * 512) : B2;
        i32x4 t0 = src[tid], t1 = src[256 + tid];
        bstage[nxt][tid]       = t0;
        bstage[nxt][256 + tid] = t1;
        const float* p = (s < 4 ? prowS : (s < 8 ? prowR : prowE)) + (s & 3) * 32 + hi * 8;
        float4 f0 = *(const float4*)p;
        float4 f1 = *(const float4*)(p + 4);
        frag_u a;
        a.i[0] = pkbf2(f0.x, f0.y); a.i[1] = pkbf2(f0.z, f0.w);
        a.i[2] = pkbf2(f1.x, f1.y); a.i[3] = pkbf2(f1.z, f1.w);
        #pragma unroll
        for (int ct = 0; ct < 8; ++ct) {
            frag_u b; b.i = bstage[cur][ct * 64 + lane];
            acc[ct] = mfma_bf16(a.s, b.s, acc[ct]);
        }
        __syncthreads();
    }

    // h = relu(y1+b1) -> wave-private LDS rows [16rt,16rt+16), XOR-swizzled
    #pragma unroll
    for (int ct = 0; ct < 8; ++ct) {
        float bb = b1[ct * 16 + j0];
        #pragma unroll
        for (int rg = 0; rg < 4; ++rg) {
            int row = rt * 16 + hi * 4 + rg;
            float y = fmaxf(acc[ct][rg] + bb, 0.0f);
            int addr = (row * 256 + (ct * 16 + j0) * 2) ^ ((row & 7) << 4);
            *(__hip_bfloat16*)(hbuf + addr) = __float2bfloat16(y);
        }
    }
    asm volatile("" ::: "memory");   // pin h store->load order (same-wave rows)

    // GEMM2: (64x128)@(128x128); slices 12..15, REUSE acc
    #pragma unroll
    for (int ct = 0; ct < 8; ++ct) acc[ct] = (f32x4){0.f, 0.f, 0.f, 0.f};
    {
        const int arow = rt * 16 + j0;
        for (int s2 = 0; s2 < 4; ++s2) {
            const int cur = (12 + s2) & 1, nxt = cur ^ 1;
            if (s2 < 3) {
                const i32x4* src = B2 + (s2 + 1) * 512;
                i32x4 t0 = src[tid], t1 = src[256 + tid];
                bstage[nxt][tid]       = t0;
                bstage[nxt][256 + tid] = t1;
            }
            int addr = (arow * 256 + (s2 * 32 + hi * 8) * 2) ^ ((arow & 7) << 4);
            frag_u a;
            a.i = *(const i32x4*)(hbuf + addr);
            #pragma unroll
            for (int ct = 0; ct < 8; ++ct) {
                frag_u b; b.i = bstage[cur][ct * 64 + lane];
                acc[ct] = mfma_bf16(a.s, b.s, acc[ct]);
            }
            if (s2 < 3) __syncthreads();
        }
    }

    // LayerNorm + residual write + attention logit
    float b2v[8], gv[8], bv[8], awv[8];
    #pragma unroll
    for (int ct = 0; ct < 8; ++ct) {
        int c = ct * 16 + j0;
        b2v[ct] = b2[c]; gv[ct] = g[c]; bv[ct] = beta[c]; awv[ct] = aW[c];
    }
    float abv = ab[0];
    #pragma unroll
    for (int rg = 0; rg < 4; ++rg) {
        int row = rt * 16 + hi * 4 + rg;
        long e = (long)blockIdx.x * 64 + row;
        float y[8]; float s = 0.f, sq = 0.f;
        #pragma unroll
        for (int ct = 0; ct < 8; ++ct) {
            y[ct] = acc[ct][rg] + b2v[ct];
            s += y[ct]; sq += y[ct] * y[ct];
        }
        #pragma unroll
        for (int m = 1; m <= 8; m <<= 1) { s += __shfl_xor(s, m); sq += __shfl_xor(sq, m); }
        float mu = s * (1.0f / 128.0f);
        float var = sq * (1.0f / 128.0f) - mu * mu;
        float rs = rsqrtf(var + LN_EPS);
        const float* efr = ef + (size_t)e * D;
        float* outr = out_ef + (size_t)e * D;
        unsigned short* rawr = STORE_RAW ? (rawbuf + (size_t)e * D) : nullptr;
        float lg = 0.f;
        #pragma unroll
        for (int ct = 0; ct < 8; ++ct) {
            int c = ct * 16 + j0;
            float o = (y[ct] - mu) * rs * gv[ct] + bv[ct];   // new_ef_raw
            outr[c] = o + efr[c];                            // residual output
            if (STORE_RAW) rawr[c] = f2bf(o);                // bf16 raw for gather
            lg += o * awv[ct];
        }
        #pragma unroll
        for (int m = 1; m <= 8; m <<= 1) lg += __shfl_xor(lg, m);
        if (j0 == 0) {
            float L = lg + abv;
            L = (L >= 0.f) ? L : 0.2f * L;                   // leaky_relu 0.2
            logits[e] = L;
        }
    }
}

// ---------------- per-node softmax + weighted aggregation (CSR gather, NO atomics) ----------------
// One wave per node; lane owns cols {2*lane, 2*lane+1}. Pass A: logit max.
// Pass B: ssum += w, acc += raw*w. Write agg = acc/ssum (0 for isolated nodes).
template <int USE_RAW>
__global__ __launch_bounds__(256) void k_agg(
    const int* __restrict__ rowptr, const int* __restrict__ elist,
    const float* __restrict__ logits, const unsigned int* __restrict__ raw32,
    const float* __restrict__ out_ef, const float* __restrict__ ef,
    float* __restrict__ agg)
{
    const int tid = threadIdx.x, lane = tid & 63, w = tid >> 6;
    const int r = blockIdx.x * 4 + w;                // grid*4 == N_NODES exactly
    const int beg = rowptr[r], end = rowptr[r + 1];

    float mx = -3.4e38f;
    for (int i = beg; i < end; ++i) mx = fmaxf(mx, logits[elist[i]]);

    float ssum = 0.f, ax = 0.f, ay = 0.f;
    for (int i = beg; i < end; ++i) {
        int e = elist[i];
        float wt = __expf(logits[e] - mx);
        ssum += wt;
        if (USE_RAW) {
            unsigned int u = raw32[(size_t)e * 64 + lane];
            ax += bf2f((unsigned short)(u & 0xffffu)) * wt;
            ay += bf2f((unsigned short)(u >> 16)) * wt;
        } else {
            float2 o = ((const float2*)out_ef)[(size_t)e * 64 + lane];
            float2 f = ((const float2*)ef)[(size_t)e * 64 + lane];
            ax += (o.x - f.x) * wt;
            ay += (o.y - f.y) * wt;
        }
    }
    float inv = (ssum > 0.f) ? 1.0f / ssum : 0.0f;
    ((float2*)agg)[(size_t)r * 64 + lane] = make_float2(ax * inv, ay * inv);
}

// ---------------- node MLP + LN + residual (barrier-free template, proven) ----------------
__global__ __launch_bounds__(256, 4) void k_node(
    const float* __restrict__ nf, const float* __restrict__ agg,
    const s16x8* __restrict__ B1, const s16x8* __restrict__ B2,
    const float* __restrict__ b1, const float* __restrict__ b2,
    const float* __restrict__ g, const float* __restrict__ beta,
    float* __restrict__ out_nf)
{
    __shared__ __align__(16) char hbuf[64 * 128 * 2];   // 16 KB
    const int tid = threadIdx.x, lane = tid & 63, rt = tid >> 6;
    const int j0 = lane & 15, hi = lane >> 4;

    long nA = (long)blockIdx.x * 64 + rt * 16 + j0;
    if (nA >= N_NODES) nA = 0;                           // pad rows: safe reads, writes guarded
    const float* __restrict__ prowN = nf  + (size_t)nA * D;
    const float* __restrict__ prowA = agg + (size_t)nA * D;

    f32x4 acc[8];
    #pragma unroll
    for (int ct = 0; ct < 8; ++ct) acc[ct] = (f32x4){0.f, 0.f, 0.f, 0.f};
    #pragma unroll
    for (int ks = 0; ks < 8; ++ks) {
        const float* p = (ks < 4 ? prowN : prowA) + (ks & 3) * 32 + hi * 8;
        float4 f0 = *(const float4*)p;
        float4 f1 = *(const float4*)(p + 4);
        frag_u a;
        a.i[0] = pkbf2(f0.x, f0.y); a.i[1] = pkbf2(f0.z, f0.w);
        a.i[2] = pkbf2(f1.x, f1.y); a.i[3] = pkbf2(f1.z, f1.w);
        #pragma unroll
        for (int ct = 0; ct < 8; ++ct)
            acc[ct] = mfma_bf16(a.s, B1[(ks * 8 + ct) * 64 + lane], acc[ct]);
    }

    #pragma unroll
    for (int ct = 0; ct < 8; ++ct) {
        float bb = b1[ct * 16 + j0];
        #pragma unroll
        for (int rg = 0; rg < 4; ++rg) {
            int row = rt * 16 + hi * 4 + rg;
            float y = fmaxf(acc[ct][rg] + bb, 0.0f);
            int addr = (row * 256 + (ct * 16 + j0) * 2) ^ ((row & 7) << 4);
            *(__hip_bfloat16*)(hbuf + addr) = __float2bfloat16(y);
        }
    }
    asm volatile("" ::: "memory");

    // GEMM2 — reuse acc
    #pragma unroll
    for (int ct = 0; ct < 8; ++ct) acc[ct] = (f32x4){0.f, 0.f, 0.f, 0.f};
    {
        int arow = rt * 16 + j0;
        #pragma unroll
        for (int ks = 0; ks < 4; ++ks) {
            int addr = (arow * 256 + (ks * 32 + hi * 8) * 2) ^ ((arow & 7) << 4);
            frag_u a;
            a.i = *(const i32x4*)(hbuf + addr);
            #pragma unroll
            for (int ct = 0; ct < 8; ++ct)
                acc[ct] = mfma_bf16(a.s, B2[(ks * 8 + ct) * 64 + lane], acc[ct]);
        }
    }

    float b2v[8], gv[8], bv[8];
    #pragma unroll
    for (int ct = 0; ct < 8; ++ct) {
        int c = ct * 16 + j0;
        b2v[ct] = b2[c]; gv[ct] = g[c]; bv[ct] = beta[c];
    }
    #pragma unroll
    for (int rg = 0; rg < 4; ++rg) {
        int row = rt * 16 + hi * 4 + rg;
        long n = (long)blockIdx.x * 64 + row;
        float y[8]; float s = 0.f, sq = 0.f;
        #pragma unroll
        for (int ct = 0; ct < 8; ++ct) {
            y[ct] = acc[ct][rg] + b2v[ct];
            s += y[ct]; sq += y[ct] * y[ct];
        }
        #pragma unroll
        for (int m = 1; m <= 8; m <<= 1) { s += __shfl_xor(s, m); sq += __shfl_xor(sq, m); }
        float mu = s * (1.0f / 128.0f);
        float var = sq * (1.0f / 128.0f) - mu * mu;
        float rs = rsqrtf(var + LN_EPS);
        if (n < N_NODES) {
            const float* nfr = nf + (size_t)n * D;
            float* outr = out_nf + (size_t)n * D;
            #pragma unroll
            for (int ct = 0; ct < 8; ++ct) {
                int c = ct * 16 + j0;
                float o = (y[ct] - mu) * rs * gv[ct] + bv[ct];
                outr[c] = o + nfr[c];                        // + node residual
            }
        }
    }
}

extern "C" void kernel_launch(void* const* d_in, const int* in_sizes, int n_in,
                              void* d_out, int out_size, void* d_ws, size_t ws_size,
                              hipStream_t stream)
{
    (void)in_sizes; (void)n_in; (void)out_size;
    const float* nf    = (const float*)d_in[0];
    const float* ef    = (const float*)d_in[1];
    const int*   snd   = (const int*)d_in[2];
    const int*   rcv   = (const int*)d_in[3];
    const float* eW1   = (const float*)d_in[4];
    const float* eb1   = (const float*)d_in[5];
    const float* eW2   = (const float*)d_in[6];
    const float* eb2   = (const float*)d_in[7];
    const float* eg    = (const float*)d_in[8];
    const float* ebeta = (const float*)d_in[9];
    const float* nW1   = (const float*)d_in[10];
    const float* nb1   = (const float*)d_in[11];
    const float* nW2   = (const float*)d_in[12];
    const float* nb2   = (const float*)d_in[13];
    const float* ng    = (const float*)d_in[14];
    const float* nbeta = (const float*)d_in[15];
    const float* aW    = (const float*)d_in[16];
    const float* ab    = (const float*)d_in[17];

    float* out_nf = (float*)d_out;
    float* out_ef = out_nf + (size_t)N_NODES * D;
    char*  ws     = (char*)d_ws;

    const bool use_raw = (ws_size >= WS_NEED_RAW);   // constant per-harness -> deterministic

    k_init<<<196, 256, 0, stream>>>(eW1, eW2, nW1, nW2, ws);

    k_count<<<(N_EDGES + 255) / 256, 256, 0, stream>>>(rcv, (int*)(ws + DEG_OFF));
    k_scan<<<1, 256, 0, stream>>>((const int*)(ws + DEG_OFF), (int*)(ws + ROWPTR_OFF));
    k_fill<<<(N_EDGES + 255) / 256, 256, 0, stream>>>(
        rcv, (const int*)(ws + ROWPTR_OFF), (int*)(ws + CURSOR_OFF), (int*)(ws + ELIST_OFF));

    if (use_raw) {
        k_edge<1><<<N_EDGES / 64, 256, 0, stream>>>(
            nf, ef, snd, rcv,
            (const i32x4*)(ws + W1P_OFF), (const i32x4*)(ws + W2P_OFF),
            eb1, eb2, eg, ebeta, aW, ab,
            out_ef, (float*)(ws + LOGITS_OFF), (unsigned short*)(ws + RAW_OFF));
        k_agg<1><<<N_NODES / 4, 256, 0, stream>>>(
            (const int*)(ws + ROWPTR_OFF), (const int*)(ws + ELIST_OFF),
            (const float*)(ws + LOGITS_OFF), (const unsigned int*)(ws + RAW_OFF),
            nullptr, nullptr, (float*)(ws + AGG_OFF));
    } else {
        k_edge<0><<<N_EDGES / 64, 256, 0, stream>>>(
            nf, ef, snd, rcv,
            (const i32x4*)(ws + W1P_OFF), (const i32x4*)(ws + W2P_OFF),
            eb1, eb2, eg, ebeta, aW, ab,
            out_ef, (float*)(ws + LOGITS_OFF), nullptr);
        k_agg<0><<<N_NODES / 4, 256, 0, stream>>>(
            (const int*)(ws + ROWPTR_OFF), (const int*)(ws + ELIST_OFF),
            (const float*)(ws + LOGITS_OFF), nullptr,
            out_ef, ef, (float*)(ws + AGG_OFF));
    }

    k_node<<<(N_NODES + 63) / 64, 256, 0, stream>>>(
        nf, (const float*)(ws + AGG_OFF),
        (const s16x8*)(ws + NW1P_OFF), (const s16x8*)(ws + NW2P_OFF),
        nb1, nb2, ng, nbeta, out_nf);
}

// Round 12
// 595.290 us; speedup vs baseline: 1.1358x; 1.0979x over previous
//
#include <hip/hip_runtime.h>
#include <hip/hip_bf16.h>

#define N_NODES 50000
#define N_EDGES 600000
#define D 128
#define LN_EPS 1e-5f

typedef float f32x4 __attribute__((ext_vector_type(4)));
typedef int   i32x4 __attribute__((ext_vector_type(4)));
typedef short s16x8 __attribute__((ext_vector_type(8)));   // 8 bf16 = 4 VGPRs

// ---- workspace byte offsets (all 64B-aligned where it matters) ----
#define W1P_OFF     0u          // 384x128 bf16 packed frags (98304 B)
#define W2P_OFF     98304u      // 128x128 bf16 (32768 B)
#define NW1P_OFF    131072u     // 256x128 bf16 (65536 B)
#define NW2P_OFF    196608u     // 128x128 bf16 (32768 B)
#define DEG_OFF     229376u     // 50000 i32   -> 429376
#define ROWPTR_OFF  429440u     // 50001 i32   -> 629444
#define LOGITS_OFF  629504u     // 600000 f32  -> 3029504
#define CURSOR_OFF  3029504u    // 50000 i32   -> 3229504
#define ELIST_OFF   3229504u    // 600000 i32  -> 5629504
#define AGG_OFF     5629504u    // 50000x128 f32 -> 31229504
#define RAW_OFF     31229504u   // 600000x128 bf16 (153.6 MB), optional
#define WS_NEED_RAW (RAW_OFF + (size_t)N_EDGES * D * 2)    // 184829504 B

static __device__ __forceinline__ unsigned short f2bf(float f) {
    unsigned int u = __float_as_uint(f);
    u = (u + 0x7FFFu + ((u >> 16) & 1u)) >> 16;   // RNE f32->bf16
    return (unsigned short)u;
}
static __device__ __forceinline__ float bf2f(unsigned short h) {
    return __uint_as_float(((unsigned int)h) << 16);
}
// pack two f32 -> bf16x2 in one int (compiler folds to v_cvt_pk_bf16_f32)
static __device__ __forceinline__ int pkbf2(float a, float b) {
    union { __hip_bfloat16 h[2]; int i; } u;
    u.h[0] = __float2bfloat16(a);
    u.h[1] = __float2bfloat16(b);
    return u.i;
}
union frag_u { i32x4 i; s16x8 s; };
// D = A(16x32)*B(32x16)+C. A: lane row=l&15, k=8*(l>>4)+e. B: col=l&15, k=8*(l>>4)+e.
// C/D: col=lane&15, row=(lane>>4)*4+reg  [m89]
static __device__ __forceinline__ f32x4 mfma_bf16(s16x8 a, s16x8 b, f32x4 c) {
    return __builtin_amdgcn_mfma_f32_16x16x32_bf16(a, b, c, 0, 0, 0);
}

// ---------------- init: pack weights into MFMA frag order; zero CSR counters ----------------
__global__ void k_init(const float* __restrict__ eW1, const float* __restrict__ eW2,
                       const float* __restrict__ nW1, const float* __restrict__ nW2,
                       char* __restrict__ ws) {
    int idx = blockIdx.x * 256 + threadIdx.x;
    if (idx < N_NODES) {
        ((int*)(ws + DEG_OFF))[idx] = 0;
        ((int*)(ws + CURSOR_OFF))[idx] = 0;
    }
    // packed layout: bf16 i = ((ks*8+ct)*64+lane)*8+e ; k=ks*32+(lane>>4)*8+e ; j=ct*16+(lane&15)
    int e = idx & 7, lane = (idx >> 3) & 63, ct = (idx >> 9) & 7, ks = idx >> 12;
    int k = ks * 32 + (lane >> 4) * 8 + e;
    int j = ct * 16 + (lane & 15);
    if (idx < 12 * 4096) ((unsigned short*)(ws + W1P_OFF))[idx]  = f2bf(eW1[k * 128 + j]);
    if (idx < 4 * 4096)  ((unsigned short*)(ws + W2P_OFF))[idx]  = f2bf(eW2[k * 128 + j]);
    if (idx < 8 * 4096)  ((unsigned short*)(ws + NW1P_OFF))[idx] = f2bf(nW1[k * 128 + j]);
    if (idx < 4 * 4096)  ((unsigned short*)(ws + NW2P_OFF))[idx] = f2bf(nW2[k * 128 + j]);
}

// ---------------- CSR build: count / scan / fill ----------------
__global__ void k_count(const int* __restrict__ rcv, int* __restrict__ deg) {
    int e = blockIdx.x * 256 + threadIdx.x;
    if (e < N_EDGES) atomicAdd(&deg[rcv[e]], 1);
}

__global__ void k_scan(const int* __restrict__ deg, int* __restrict__ rowptr) {
    __shared__ int part[256];
    const int tid = threadIdx.x;
    const int CH = (N_NODES + 255) / 256;           // 196 per thread
    const int base = tid * CH;
    int s = 0;
    for (int i = 0; i < CH; ++i) { int idx = base + i; if (idx < N_NODES) s += deg[idx]; }
    part[tid] = s;
    __syncthreads();
    if (tid == 0) {
        int run = 0;
        for (int j = 0; j < 256; ++j) { int t = part[j]; part[j] = run; run += t; }
        rowptr[N_NODES] = run;                      // = N_EDGES
    }
    __syncthreads();
    int run = part[tid];
    for (int i = 0; i < CH; ++i) {
        int idx = base + i;
        if (idx < N_NODES) { rowptr[idx] = run; run += deg[idx]; }
    }
}

__global__ void k_fill(const int* __restrict__ rcv, const int* __restrict__ rowptr,
                       int* __restrict__ cursor, int* __restrict__ elist) {
    int e = blockIdx.x * 256 + threadIdx.x;
    if (e >= N_EDGES) return;
    int r = rcv[e];
    int slot = atomicAdd(&cursor[r], 1);
    elist[rowptr[r] + slot] = e;
}

// ---------------- edge MLP + LN + residual + logits ----------------
// One-tile per wave (proven mapping) + double-buffered LDS B slices (R8) with
// conflict-free staging (R9). Unchanged from R10.
template <int STORE_RAW>
__global__ __launch_bounds__(256, 4) void k_edge(
    const float* __restrict__ nf, const float* __restrict__ ef,
    const int* __restrict__ snd, const int* __restrict__ rcv,
    const i32x4* __restrict__ B1, const i32x4* __restrict__ B2,
    const float* __restrict__ b1, const float* __restrict__ b2,
    const float* __restrict__ g, const float* __restrict__ beta,
    const float* __restrict__ aW, const float* __restrict__ ab,
    float* __restrict__ out_ef, float* __restrict__ logits,
    unsigned short* __restrict__ rawbuf)
{
    __shared__ __align__(16) char  hbuf[64 * 128 * 2];   // 16 KB, wave-private rows
    __shared__ __align__(16) i32x4 bstage[2][512];       // 2 x 8 KB B slices
    const int tid = threadIdx.x, lane = tid & 63, rt = tid >> 6;
    const int j0 = lane & 15, hi = lane >> 4;

    const long eA = (long)blockIdx.x * 64 + rt * 16 + j0;
    const int sA = snd[eA], rA = rcv[eA];
    const float* __restrict__ prowS = nf + (size_t)sA * D;
    const float* __restrict__ prowR = nf + (size_t)rA * D;
    const float* __restrict__ prowE = ef + (size_t)eA * D;

    // prologue: stage slice 0 (B1 ks=0); 16B-stride writes = conflict-free
    bstage[0][tid]       = B1[tid];
    bstage[0][256 + tid] = B1[256 + tid];
    __syncthreads();

    // GEMM1: (64x384)@(384x128); slices s=0..11
    f32x4 acc[8];
    #pragma unroll
    for (int ct = 0; ct < 8; ++ct) acc[ct] = (f32x4){0.f, 0.f, 0.f, 0.f};
    for (int s = 0; s < 12; ++s) {
        const int cur = s & 1, nxt = cur ^ 1;
        const i32x4* src = (s + 1 < 12) ? (B1 + (s + 1) * 512) : B2;
        i32x4 t0 = src[tid], t1 = src[256 + tid];
        bstage[nxt][tid]       = t0;
        bstage[nxt][256 + tid] = t1;
        const float* p = (s < 4 ? prowS : (s < 8 ? prowR : prowE)) + (s & 3) * 32 + hi * 8;
        float4 f0 = *(const float4*)p;
        float4 f1 = *(const float4*)(p + 4);
        frag_u a;
        a.i[0] = pkbf2(f0.x, f0.y); a.i[1] = pkbf2(f0.z, f0.w);
        a.i[2] = pkbf2(f1.x, f1.y); a.i[3] = pkbf2(f1.z, f1.w);
        #pragma unroll
        for (int ct = 0; ct < 8; ++ct) {
            frag_u b; b.i = bstage[cur][ct * 64 + lane];
            acc[ct] = mfma_bf16(a.s, b.s, acc[ct]);
        }
        __syncthreads();
    }

    // h = relu(y1+b1) -> wave-private LDS rows [16rt,16rt+16), XOR-swizzled
    #pragma unroll
    for (int ct = 0; ct < 8; ++ct) {
        float bb = b1[ct * 16 + j0];
        #pragma unroll
        for (int rg = 0; rg < 4; ++rg) {
            int row = rt * 16 + hi * 4 + rg;
            float y = fmaxf(acc[ct][rg] + bb, 0.0f);
            int addr = (row * 256 + (ct * 16 + j0) * 2) ^ ((row & 7) << 4);
            *(__hip_bfloat16*)(hbuf + addr) = __float2bfloat16(y);
        }
    }
    asm volatile("" ::: "memory");   // pin h store->load order (same-wave rows)

    // GEMM2: (64x128)@(128x128); slices 12..15, REUSE acc
    #pragma unroll
    for (int ct = 0; ct < 8; ++ct) acc[ct] = (f32x4){0.f, 0.f, 0.f, 0.f};
    {
        const int arow = rt * 16 + j0;
        for (int s2 = 0; s2 < 4; ++s2) {
            const int cur = (12 + s2) & 1, nxt = cur ^ 1;
            if (s2 < 3) {
                const i32x4* src = B2 + (s2 + 1) * 512;
                i32x4 t0 = src[tid], t1 = src[256 + tid];
                bstage[nxt][tid]       = t0;
                bstage[nxt][256 + tid] = t1;
            }
            int addr = (arow * 256 + (s2 * 32 + hi * 8) * 2) ^ ((arow & 7) << 4);
            frag_u a;
            a.i = *(const i32x4*)(hbuf + addr);
            #pragma unroll
            for (int ct = 0; ct < 8; ++ct) {
                frag_u b; b.i = bstage[cur][ct * 64 + lane];
                acc[ct] = mfma_bf16(a.s, b.s, acc[ct]);
            }
            if (s2 < 3) __syncthreads();
        }
    }

    // LayerNorm + residual write + attention logit
    float b2v[8], gv[8], bv[8], awv[8];
    #pragma unroll
    for (int ct = 0; ct < 8; ++ct) {
        int c = ct * 16 + j0;
        b2v[ct] = b2[c]; gv[ct] = g[c]; bv[ct] = beta[c]; awv[ct] = aW[c];
    }
    float abv = ab[0];
    #pragma unroll
    for (int rg = 0; rg < 4; ++rg) {
        int row = rt * 16 + hi * 4 + rg;
        long e = (long)blockIdx.x * 64 + row;
        float y[8]; float s = 0.f, sq = 0.f;
        #pragma unroll
        for (int ct = 0; ct < 8; ++ct) {
            y[ct] = acc[ct][rg] + b2v[ct];
            s += y[ct]; sq += y[ct] * y[ct];
        }
        #pragma unroll
        for (int m = 1; m <= 8; m <<= 1) { s += __shfl_xor(s, m); sq += __shfl_xor(sq, m); }
        float mu = s * (1.0f / 128.0f);
        float var = sq * (1.0f / 128.0f) - mu * mu;
        float rs = rsqrtf(var + LN_EPS);
        const float* efr = ef + (size_t)e * D;
        float* outr = out_ef + (size_t)e * D;
        unsigned short* rawr = STORE_RAW ? (rawbuf + (size_t)e * D) : nullptr;
        float lg = 0.f;
        #pragma unroll
        for (int ct = 0; ct < 8; ++ct) {
            int c = ct * 16 + j0;
            float o = (y[ct] - mu) * rs * gv[ct] + bv[ct];   // new_ef_raw
            outr[c] = o + efr[c];                            // residual output
            if (STORE_RAW) rawr[c] = f2bf(o);                // bf16 raw for gather
            lg += o * awv[ct];
        }
        #pragma unroll
        for (int m = 1; m <= 8; m <<= 1) lg += __shfl_xor(lg, m);
        if (j0 == 0) {
            float L = lg + abv;
            L = (L >= 0.f) ? L : 0.2f * L;                   // leaky_relu 0.2
            logits[e] = L;
        }
    }
}

// ---------------- per-node softmax + weighted aggregation (CSR gather, NO atomics) ----------------
// R11: LANE-PARALLEL edge handling. Lane i owns edge beg+i (chunks of 64):
// logits load + exp are parallel; shuffle-reduce max/sum; row-gather loop has all
// addresses upfront (independent loads pipeline, no dependent-latency chain).
template <int USE_RAW>
__global__ __launch_bounds__(256) void k_agg(
    const int* __restrict__ rowptr, const int* __restrict__ elist,
    const float* __restrict__ logits, const unsigned int* __restrict__ raw32,
    const float* __restrict__ out_ef, const float* __restrict__ ef,
    float* __restrict__ agg)
{
    const int tid = threadIdx.x, lane = tid & 63, w = tid >> 6;
    const int r = blockIdx.x * 4 + w;                // grid*4 == N_NODES exactly
    const int beg = rowptr[r], end = rowptr[r + 1];

    // pass A: lane-parallel logit max
    float mx = -3.4e38f;
    for (int cb = beg; cb < end; cb += 64) {
        int i = cb + lane;
        float lg = (i < end) ? logits[elist[i]] : -3.4e38f;
        mx = fmaxf(mx, lg);
    }
    #pragma unroll
    for (int m = 1; m <= 32; m <<= 1) mx = fmaxf(mx, __shfl_xor(mx, m));

    // pass B: lane-parallel weights; broadcast per-edge for the coalesced row gather
    float ssum = 0.f, ax = 0.f, ay = 0.f;
    for (int cb = beg; cb < end; cb += 64) {
        int i = cb + lane;
        int cnt = min(64, end - cb);
        int e = (i < end) ? elist[i] : 0;
        float wt = (i < end) ? __expf(logits[e] - mx) : 0.f;
        ssum += wt;
        for (int j = 0; j < cnt; ++j) {
            int   ej = __shfl(e, j);
            float wj = __shfl(wt, j);
            if (USE_RAW) {
                unsigned int u = raw32[(size_t)ej * 64 + lane];
                ax += bf2f((unsigned short)(u & 0xffffu)) * wj;
                ay += bf2f((unsigned short)(u >> 16)) * wj;
            } else {
                float2 o = ((const float2*)out_ef)[(size_t)ej * 64 + lane];
                float2 f = ((const float2*)ef)[(size_t)ej * 64 + lane];
                ax += (o.x - f.x) * wj;
                ay += (o.y - f.y) * wj;
            }
        }
    }
    #pragma unroll
    for (int m = 1; m <= 32; m <<= 1) ssum += __shfl_xor(ssum, m);
    float inv = (ssum > 0.f) ? 1.0f / ssum : 0.0f;
    ((float2*)agg)[(size_t)r * 64 + lane] = make_float2(ax * inv, ay * inv);
}

// ---------------- node MLP + LN + residual (barrier-free template, proven) ----------------
__global__ __launch_bounds__(256, 4) void k_node(
    const float* __restrict__ nf, const float* __restrict__ agg,
    const s16x8* __restrict__ B1, const s16x8* __restrict__ B2,
    const float* __restrict__ b1, const float* __restrict__ b2,
    const float* __restrict__ g, const float* __restrict__ beta,
    float* __restrict__ out_nf)
{
    __shared__ __align__(16) char hbuf[64 * 128 * 2];   // 16 KB
    const int tid = threadIdx.x, lane = tid & 63, rt = tid >> 6;
    const int j0 = lane & 15, hi = lane >> 4;

    long nA = (long)blockIdx.x * 64 + rt * 16 + j0;
    if (nA >= N_NODES) nA = 0;                           // pad rows: safe reads, writes guarded
    const float* __restrict__ prowN = nf  + (size_t)nA * D;
    const float* __restrict__ prowA = agg + (size_t)nA * D;

    f32x4 acc[8];
    #pragma unroll
    for (int ct = 0; ct < 8; ++ct) acc[ct] = (f32x4){0.f, 0.f, 0.f, 0.f};
    #pragma unroll
    for (int ks = 0; ks < 8; ++ks) {
        const float* p = (ks < 4 ? prowN : prowA) + (ks & 3) * 32 + hi * 8;
        float4 f0 = *(const float4*)p;
        float4 f1 = *(const float4*)(p + 4);
        frag_u a;
        a.i[0] = pkbf2(f0.x, f0.y); a.i[1] = pkbf2(f0.z, f0.w);
        a.i[2] = pkbf2(f1.x, f1.y); a.i[3] = pkbf2(f1.z, f1.w);
        #pragma unroll
        for (int ct = 0; ct < 8; ++ct)
            acc[ct] = mfma_bf16(a.s, B1[(ks * 8 + ct) * 64 + lane], acc[ct]);
    }

    #pragma unroll
    for (int ct = 0; ct < 8; ++ct) {
        float bb = b1[ct * 16 + j0];
        #pragma unroll
        for (int rg = 0; rg < 4; ++rg) {
            int row = rt * 16 + hi * 4 + rg;
            float y = fmaxf(acc[ct][rg] + bb, 0.0f);
            int addr = (row * 256 + (ct * 16 + j0) * 2) ^ ((row & 7) << 4);
            *(__hip_bfloat16*)(hbuf + addr) = __float2bfloat16(y);
        }
    }
    asm volatile("" ::: "memory");

    // GEMM2 — reuse acc
    #pragma unroll
    for (int ct = 0; ct < 8; ++ct) acc[ct] = (f32x4){0.f, 0.f, 0.f, 0.f};
    {
        int arow = rt * 16 + j0;
        #pragma unroll
        for (int ks = 0; ks < 4; ++ks) {
            int addr = (arow * 256 + (ks * 32 + hi * 8) * 2) ^ ((arow & 7) << 4);
            frag_u a;
            a.i = *(const i32x4*)(hbuf + addr);
            #pragma unroll
            for (int ct = 0; ct < 8; ++ct)
                acc[ct] = mfma_bf16(a.s, B2[(ks * 8 + ct) * 64 + lane], acc[ct]);
        }
    }

    float b2v[8], gv[8], bv[8];
    #pragma unroll
    for (int ct = 0; ct < 8; ++ct) {
        int c = ct * 16 + j0;
        b2v[ct] = b2[c]; gv[ct] = g[c]; bv[ct] = beta[c];
    }
    #pragma unroll
    for (int rg = 0; rg < 4; ++rg) {
        int row = rt * 16 + hi * 4 + rg;
        long n = (long)blockIdx.x * 64 + row;
        float y[8]; float s = 0.f, sq = 0.f;
        #pragma unroll
        for (int ct = 0; ct < 8; ++ct) {
            y[ct] = acc[ct][rg] + b2v[ct];
            s += y[ct]; sq += y[ct] * y[ct];
        }
        #pragma unroll
        for (int m = 1; m <= 8; m <<= 1) { s += __shfl_xor(s, m); sq += __shfl_xor(sq, m); }
        float mu = s * (1.0f / 128.0f);
        float var = sq * (1.0f / 128.0f) - mu * mu;
        float rs = rsqrtf(var + LN_EPS);
        if (n < N_NODES) {
            const float* nfr = nf + (size_t)n * D;
            float* outr = out_nf + (size_t)n * D;
            #pragma unroll
            for (int ct = 0; ct < 8; ++ct) {
                int c = ct * 16 + j0;
                float o = (y[ct] - mu) * rs * gv[ct] + bv[ct];
                outr[c] = o + nfr[c];                        // + node residual
            }
        }
    }
}

extern "C" void kernel_launch(void* const* d_in, const int* in_sizes, int n_in,
                              void* d_out, int out_size, void* d_ws, size_t ws_size,
                              hipStream_t stream)
{
    (void)in_sizes; (void)n_in; (void)out_size;
    const float* nf    = (const float*)d_in[0];
    const float* ef    = (const float*)d_in[1];
    const int*   snd   = (const int*)d_in[2];
    const int*   rcv   = (const int*)d_in[3];
    const float* eW1   = (const float*)d_in[4];
    const float* eb1   = (const float*)d_in[5];
    const float* eW2   = (const float*)d_in[6];
    const float* eb2   = (const float*)d_in[7];
    const float* eg    = (const float*)d_in[8];
    const float* ebeta = (const float*)d_in[9];
    const float* nW1   = (const float*)d_in[10];
    const float* nb1   = (const float*)d_in[11];
    const float* nW2   = (const float*)d_in[12];
    const float* nb2   = (const float*)d_in[13];
    const float* ng    = (const float*)d_in[14];
    const float* nbeta = (const float*)d_in[15];
    const float* aW    = (const float*)d_in[16];
    const float* ab    = (const float*)d_in[17];

    float* out_nf = (float*)d_out;
    float* out_ef = out_nf + (size_t)N_NODES * D;
    char*  ws     = (char*)d_ws;

    const bool use_raw = (ws_size >= WS_NEED_RAW);   // constant per-harness -> deterministic

    k_init<<<196, 256, 0, stream>>>(eW1, eW2, nW1, nW2, ws);

    k_count<<<(N_EDGES + 255) / 256, 256, 0, stream>>>(rcv, (int*)(ws + DEG_OFF));
    k_scan<<<1, 256, 0, stream>>>((const int*)(ws + DEG_OFF), (int*)(ws + ROWPTR_OFF));
    k_fill<<<(N_EDGES + 255) / 256, 256, 0, stream>>>(
        rcv, (const int*)(ws + ROWPTR_OFF), (int*)(ws + CURSOR_OFF), (int*)(ws + ELIST_OFF));

    if (use_raw) {
        k_edge<1><<<N_EDGES / 64, 256, 0, stream>>>(
            nf, ef, snd, rcv,
            (const i32x4*)(ws + W1P_OFF), (const i32x4*)(ws + W2P_OFF),
            eb1, eb2, eg, ebeta, aW, ab,
            out_ef, (float*)(ws + LOGITS_OFF), (unsigned short*)(ws + RAW_OFF));
        k_agg<1><<<N_NODES / 4, 256, 0, stream>>>(
            (const int*)(ws + ROWPTR_OFF), (const int*)(ws + ELIST_OFF),
            (const float*)(ws + LOGITS_OFF), (const unsigned int*)(ws + RAW_OFF),
            nullptr, nullptr, (float*)(ws + AGG_OFF));
    } else {
        k_edge<0><<<N_EDGES / 64, 256, 0, stream>>>(
            nf, ef, snd, rcv,
            (const i32x4*)(ws + W1P_OFF), (const i32x4*)(ws + W2P_OFF),
            eb1, eb2, eg, ebeta, aW, ab,
            out_ef, (float*)(ws + LOGITS_OFF), nullptr);
        k_agg<0><<<N_NODES / 4, 256, 0, stream>>>(
            (const int*)(ws + ROWPTR_OFF), (const int*)(ws + ELIST_OFF),
            (const float*)(ws + LOGITS_OFF), nullptr,
            out_ef, ef, (float*)(ws + AGG_OFF));
    }

    k_node<<<(N_NODES + 63) / 64, 256, 0, stream>>>(
        nf, (const float*)(ws + AGG_OFF),
        (const s16x8*)(ws + NW1P_OFF), (const s16x8*)(ws + NW2P_OFF),
        nb1, nb2, ng, nbeta, out_nf);
}

// Round 13
// 583.636 us; speedup vs baseline: 1.1585x; 1.0200x over previous
//
#include <hip/hip_runtime.h>
#include <hip/hip_bf16.h>

#define N_NODES 50000
#define N_EDGES 600000
#define D 128
#define LN_EPS 1e-5f

typedef float f32x4 __attribute__((ext_vector_type(4)));
typedef int   i32x4 __attribute__((ext_vector_type(4)));
typedef short s16x8 __attribute__((ext_vector_type(8)));   // 8 bf16 = 4 VGPRs

// ---- workspace byte offsets (all 64B-aligned where it matters) ----
#define W1P_OFF     0u          // 384x128 bf16 packed frags (98304 B)
#define W2P_OFF     98304u      // 128x128 bf16 (32768 B)
#define NW1P_OFF    131072u     // 256x128 bf16 (65536 B)
#define NW2P_OFF    196608u     // 128x128 bf16 (32768 B)
#define DEG_OFF     229376u     // 50000 i32   -> 429376
#define ROWPTR_OFF  429440u     // 50001 i32   -> 629444
#define LOGITS_OFF  629504u     // 600000 f32  -> 3029504
#define CURSOR_OFF  3029504u    // 50000 i32   -> 3229504
#define ELIST_OFF   3229504u    // 600000 i32  -> 5629504
#define AGG_OFF     5629504u    // 50000x128 f32 -> 31229504
#define RAW_OFF     31229504u   // 600000x128 bf16 (153.6 MB), optional
#define WS_NEED_RAW (RAW_OFF + (size_t)N_EDGES * D * 2)    // 184829504 B

static __device__ __forceinline__ unsigned short f2bf(float f) {
    unsigned int u = __float_as_uint(f);
    u = (u + 0x7FFFu + ((u >> 16) & 1u)) >> 16;   // RNE f32->bf16
    return (unsigned short)u;
}
static __device__ __forceinline__ float bf2f(unsigned short h) {
    return __uint_as_float(((unsigned int)h) << 16);
}
// pack two f32 -> bf16x2 in one int (compiler folds to v_cvt_pk_bf16_f32)
static __device__ __forceinline__ int pkbf2(float a, float b) {
    union { __hip_bfloat16 h[2]; int i; } u;
    u.h[0] = __float2bfloat16(a);
    u.h[1] = __float2bfloat16(b);
    return u.i;
}
union frag_u { i32x4 i; s16x8 s; };
// D = A(16x32)*B(32x16)+C. A: lane row=l&15, k=8*(l>>4)+e. B: col=l&15, k=8*(l>>4)+e.
// C/D: col=lane&15, row=(lane>>4)*4+reg  [m89]
static __device__ __forceinline__ f32x4 mfma_bf16(s16x8 a, s16x8 b, f32x4 c) {
    return __builtin_amdgcn_mfma_f32_16x16x32_bf16(a, b, c, 0, 0, 0);
}

// ---------------- init: pack weights into MFMA frag order; zero CSR counters ----------------
__global__ void k_init(const float* __restrict__ eW1, const float* __restrict__ eW2,
                       const float* __restrict__ nW1, const float* __restrict__ nW2,
                       char* __restrict__ ws) {
    int idx = blockIdx.x * 256 + threadIdx.x;
    if (idx < N_NODES) {
        ((int*)(ws + DEG_OFF))[idx] = 0;
        ((int*)(ws + CURSOR_OFF))[idx] = 0;
    }
    // packed layout: bf16 i = ((ks*8+ct)*64+lane)*8+e ; k=ks*32+(lane>>4)*8+e ; j=ct*16+(lane&15)
    int e = idx & 7, lane = (idx >> 3) & 63, ct = (idx >> 9) & 7, ks = idx >> 12;
    int k = ks * 32 + (lane >> 4) * 8 + e;
    int j = ct * 16 + (lane & 15);
    if (idx < 12 * 4096) ((unsigned short*)(ws + W1P_OFF))[idx]  = f2bf(eW1[k * 128 + j]);
    if (idx < 4 * 4096)  ((unsigned short*)(ws + W2P_OFF))[idx]  = f2bf(eW2[k * 128 + j]);
    if (idx < 8 * 4096)  ((unsigned short*)(ws + NW1P_OFF))[idx] = f2bf(nW1[k * 128 + j]);
    if (idx < 4 * 4096)  ((unsigned short*)(ws + NW2P_OFF))[idx] = f2bf(nW2[k * 128 + j]);
}

// ---------------- CSR build: count / scan / fill ----------------
__global__ void k_count(const int* __restrict__ rcv, int* __restrict__ deg) {
    int e = blockIdx.x * 256 + threadIdx.x;
    if (e < N_EDGES) atomicAdd(&deg[rcv[e]], 1);
}

__global__ void k_scan(const int* __restrict__ deg, int* __restrict__ rowptr) {
    __shared__ int part[256];
    const int tid = threadIdx.x;
    const int CH = (N_NODES + 255) / 256;           // 196 per thread
    const int base = tid * CH;
    int s = 0;
    for (int i = 0; i < CH; ++i) { int idx = base + i; if (idx < N_NODES) s += deg[idx]; }
    part[tid] = s;
    __syncthreads();
    if (tid == 0) {
        int run = 0;
        for (int j = 0; j < 256; ++j) { int t = part[j]; part[j] = run; run += t; }
        rowptr[N_NODES] = run;                      // = N_EDGES
    }
    __syncthreads();
    int run = part[tid];
    for (int i = 0; i < CH; ++i) {
        int idx = base + i;
        if (idx < N_NODES) { rowptr[idx] = run; run += deg[idx]; }
    }
}

__global__ void k_fill(const int* __restrict__ rcv, const int* __restrict__ rowptr,
                       int* __restrict__ cursor, int* __restrict__ elist) {
    int e = blockIdx.x * 256 + threadIdx.x;
    if (e >= N_EDGES) return;
    int r = rcv[e];
    int slot = atomicAdd(&cursor[r], 1);
    elist[rowptr[r] + slot] = e;
}

// ---------------- edge MLP + LN + residual + logits ----------------
// R13: software-pipelined slices. At slice s: ds_write B(s+1) FROM REGS (loaded
// last iter, no L2 wait), pack A(s) from regs, issue B(s+2)+A(s+1) loads (latency
// hidden under slice-s MFMAs + barrier). Same mapping/buffers/barriers as R12.
template <int STORE_RAW>
__global__ __launch_bounds__(256, 4) void k_edge(
    const float* __restrict__ nf, const float* __restrict__ ef,
    const int* __restrict__ snd, const int* __restrict__ rcv,
    const i32x4* __restrict__ B1, const i32x4* __restrict__ B2,
    const float* __restrict__ b1, const float* __restrict__ b2,
    const float* __restrict__ g, const float* __restrict__ beta,
    const float* __restrict__ aW, const float* __restrict__ ab,
    float* __restrict__ out_ef, float* __restrict__ logits,
    unsigned short* __restrict__ rawbuf)
{
    __shared__ __align__(16) char  hbuf[64 * 128 * 2];   // 16 KB, wave-private rows
    __shared__ __align__(16) i32x4 bstage[2][512];       // 2 x 8 KB B slices
    const int tid = threadIdx.x, lane = tid & 63, rt = tid >> 6;
    const int j0 = lane & 15, hi = lane >> 4;

    const long eA = (long)blockIdx.x * 64 + rt * 16 + j0;
    const int sA = snd[eA], rA = rcv[eA];
    const float* __restrict__ prowS = nf + (size_t)sA * D;
    const float* __restrict__ prowR = nf + (size_t)rA * D;
    const float* __restrict__ prowE = ef + (size_t)eA * D;

    // prologue: B(0) -> bstage[0]; B(1) -> regs; A(0) -> regs
    {
        i32x4 p0 = B1[tid], p1 = B1[256 + tid];
        bstage[0][tid]       = p0;
        bstage[0][256 + tid] = p1;
    }
    i32x4 t0 = B1[512 + tid], t1 = B1[768 + tid];        // B(1)
    float4 f0 = *(const float4*)(prowS + hi * 8);        // A(0): slice 0 = prowS, off 0
    float4 f1 = *(const float4*)(prowS + hi * 8 + 4);
    __syncthreads();

    // GEMM1: (64x384)@(384x128); slices s=0..11
    f32x4 acc[8];
    #pragma unroll
    for (int ct = 0; ct < 8; ++ct) acc[ct] = (f32x4){0.f, 0.f, 0.f, 0.f};
    for (int s = 0; s < 12; ++s) {
        const int cur = s & 1, nxt = cur ^ 1;
        // write B(s+1) from regs (no L2 wait); bstage[nxt] reads finished at prior barrier
        bstage[nxt][tid]       = t0;
        bstage[nxt][256 + tid] = t1;
        // pack A(s) from regs
        frag_u a;
        a.i[0] = pkbf2(f0.x, f0.y); a.i[1] = pkbf2(f0.z, f0.w);
        a.i[2] = pkbf2(f1.x, f1.y); a.i[3] = pkbf2(f1.z, f1.w);
        // issue next loads: B(s+2) (max idx 13 -> B2 slice 1), A(s+1)
        {
            const i32x4* src = (s + 2 < 12) ? (B1 + (s + 2) * 512) : (B2 + (s + 2 - 12) * 512);
            t0 = src[tid];
            t1 = src[256 + tid];
        }
        if (s < 11) {
            const int sn = s + 1;
            const float* p = (sn < 4 ? prowS : (sn < 8 ? prowR : prowE)) + (sn & 3) * 32 + hi * 8;
            f0 = *(const float4*)p;
            f1 = *(const float4*)(p + 4);
        }
        // MFMAs on slice s (loads above complete under these + the barrier)
        #pragma unroll
        for (int ct = 0; ct < 8; ++ct) {
            frag_u b; b.i = bstage[cur][ct * 64 + lane];
            acc[ct] = mfma_bf16(a.s, b.s, acc[ct]);
        }
        __syncthreads();
    }

    // h = relu(y1+b1) -> wave-private LDS rows [16rt,16rt+16), XOR-swizzled
    #pragma unroll
    for (int ct = 0; ct < 8; ++ct) {
        float bb = b1[ct * 16 + j0];
        #pragma unroll
        for (int rg = 0; rg < 4; ++rg) {
            int row = rt * 16 + hi * 4 + rg;
            float y = fmaxf(acc[ct][rg] + bb, 0.0f);
            int addr = (row * 256 + (ct * 16 + j0) * 2) ^ ((row & 7) << 4);
            *(__hip_bfloat16*)(hbuf + addr) = __float2bfloat16(y);
        }
    }
    asm volatile("" ::: "memory");   // pin h store->load order (same-wave rows)

    // GEMM2: (64x128)@(128x128); bstage[0]=B(12) staged, regs=B(13); REUSE acc
    #pragma unroll
    for (int ct = 0; ct < 8; ++ct) acc[ct] = (f32x4){0.f, 0.f, 0.f, 0.f};
    {
        const int arow = rt * 16 + j0;
        for (int s2 = 0; s2 < 4; ++s2) {
            const int cur = s2 & 1, nxt = cur ^ 1;
            if (s2 < 3) {                                  // write B(13+s2) from regs
                bstage[nxt][tid]       = t0;
                bstage[nxt][256 + tid] = t1;
            }
            if (s2 < 2) {                                  // load B(14+s2)
                const i32x4* src = B2 + (s2 + 2) * 512;
                t0 = src[tid];
                t1 = src[256 + tid];
            }
            int addr = (arow * 256 + (s2 * 32 + hi * 8) * 2) ^ ((arow & 7) << 4);
            frag_u a;
            a.i = *(const i32x4*)(hbuf + addr);
            #pragma unroll
            for (int ct = 0; ct < 8; ++ct) {
                frag_u b; b.i = bstage[cur][ct * 64 + lane];
                acc[ct] = mfma_bf16(a.s, b.s, acc[ct]);
            }
            if (s2 < 3) __syncthreads();
        }
    }

    // LayerNorm + residual write + attention logit
    float b2v[8], gv[8], bv[8], awv[8];
    #pragma unroll
    for (int ct = 0; ct < 8; ++ct) {
        int c = ct * 16 + j0;
        b2v[ct] = b2[c]; gv[ct] = g[c]; bv[ct] = beta[c]; awv[ct] = aW[c];
    }
    float abv = ab[0];
    #pragma unroll
    for (int rg = 0; rg < 4; ++rg) {
        int row = rt * 16 + hi * 4 + rg;
        long e = (long)blockIdx.x * 64 + row;
        float y[8]; float s = 0.f, sq = 0.f;
        #pragma unroll
        for (int ct = 0; ct < 8; ++ct) {
            y[ct] = acc[ct][rg] + b2v[ct];
            s += y[ct]; sq += y[ct] * y[ct];
        }
        #pragma unroll
        for (int m = 1; m <= 8; m <<= 1) { s += __shfl_xor(s, m); sq += __shfl_xor(sq, m); }
        float mu = s * (1.0f / 128.0f);
        float var = sq * (1.0f / 128.0f) - mu * mu;
        float rs = rsqrtf(var + LN_EPS);
        const float* efr = ef + (size_t)e * D;
        float* outr = out_ef + (size_t)e * D;
        unsigned short* rawr = STORE_RAW ? (rawbuf + (size_t)e * D) : nullptr;
        float lg = 0.f;
        #pragma unroll
        for (int ct = 0; ct < 8; ++ct) {
            int c = ct * 16 + j0;
            float o = (y[ct] - mu) * rs * gv[ct] + bv[ct];   // new_ef_raw
            outr[c] = o + efr[c];                            // residual output
            if (STORE_RAW) rawr[c] = f2bf(o);                // bf16 raw for gather
            lg += o * awv[ct];
        }
        #pragma unroll
        for (int m = 1; m <= 8; m <<= 1) lg += __shfl_xor(lg, m);
        if (j0 == 0) {
            float L = lg + abv;
            L = (L >= 0.f) ? L : 0.2f * L;                   // leaky_relu 0.2
            logits[e] = L;
        }
    }
}

// ---------------- per-node softmax + weighted aggregation (CSR gather, NO atomics) ----------------
// Lane-parallel (R11): lane i owns edge beg+i; shuffle-reduce max/sum; row-gather
// via per-edge broadcast so all addresses are known upfront (loads pipeline).
template <int USE_RAW>
__global__ __launch_bounds__(256) void k_agg(
    const int* __restrict__ rowptr, const int* __restrict__ elist,
    const float* __restrict__ logits, const unsigned int* __restrict__ raw32,
    const float* __restrict__ out_ef, const float* __restrict__ ef,
    float* __restrict__ agg)
{
    const int tid = threadIdx.x, lane = tid & 63, w = tid >> 6;
    const int r = blockIdx.x * 4 + w;                // grid*4 == N_NODES exactly
    const int beg = rowptr[r], end = rowptr[r + 1];

    // pass A: lane-parallel logit max
    float mx = -3.4e38f;
    for (int cb = beg; cb < end; cb += 64) {
        int i = cb + lane;
        float lg = (i < end) ? logits[elist[i]] : -3.4e38f;
        mx = fmaxf(mx, lg);
    }
    #pragma unroll
    for (int m = 1; m <= 32; m <<= 1) mx = fmaxf(mx, __shfl_xor(mx, m));

    // pass B: lane-parallel weights; broadcast per-edge for the coalesced row gather
    float ssum = 0.f, ax = 0.f, ay = 0.f;
    for (int cb = beg; cb < end; cb += 64) {
        int i = cb + lane;
        int cnt = min(64, end - cb);
        int e = (i < end) ? elist[i] : 0;
        float wt = (i < end) ? __expf(logits[e] - mx) : 0.f;
        ssum += wt;
        for (int j = 0; j < cnt; ++j) {
            int   ej = __shfl(e, j);
            float wj = __shfl(wt, j);
            if (USE_RAW) {
                unsigned int u = raw32[(size_t)ej * 64 + lane];
                ax += bf2f((unsigned short)(u & 0xffffu)) * wj;
                ay += bf2f((unsigned short)(u >> 16)) * wj;
            } else {
                float2 o = ((const float2*)out_ef)[(size_t)ej * 64 + lane];
                float2 f = ((const float2*)ef)[(size_t)ej * 64 + lane];
                ax += (o.x - f.x) * wj;
                ay += (o.y - f.y) * wj;
            }
        }
    }
    #pragma unroll
    for (int m = 1; m <= 32; m <<= 1) ssum += __shfl_xor(ssum, m);
    float inv = (ssum > 0.f) ? 1.0f / ssum : 0.0f;
    ((float2*)agg)[(size_t)r * 64 + lane] = make_float2(ax * inv, ay * inv);
}

// ---------------- node MLP + LN + residual (barrier-free template, proven) ----------------
__global__ __launch_bounds__(256, 4) void k_node(
    const float* __restrict__ nf, const float* __restrict__ agg,
    const s16x8* __restrict__ B1, const s16x8* __restrict__ B2,
    const float* __restrict__ b1, const float* __restrict__ b2,
    const float* __restrict__ g, const float* __restrict__ beta,
    float* __restrict__ out_nf)
{
    __shared__ __align__(16) char hbuf[64 * 128 * 2];   // 16 KB
    const int tid = threadIdx.x, lane = tid & 63, rt = tid >> 6;
    const int j0 = lane & 15, hi = lane >> 4;

    long nA = (long)blockIdx.x * 64 + rt * 16 + j0;
    if (nA >= N_NODES) nA = 0;                           // pad rows: safe reads, writes guarded
    const float* __restrict__ prowN = nf  + (size_t)nA * D;
    const float* __restrict__ prowA = agg + (size_t)nA * D;

    f32x4 acc[8];
    #pragma unroll
    for (int ct = 0; ct < 8; ++ct) acc[ct] = (f32x4){0.f, 0.f, 0.f, 0.f};
    #pragma unroll
    for (int ks = 0; ks < 8; ++ks) {
        const float* p = (ks < 4 ? prowN : prowA) + (ks & 3) * 32 + hi * 8;
        float4 f0 = *(const float4*)p;
        float4 f1 = *(const float4*)(p + 4);
        frag_u a;
        a.i[0] = pkbf2(f0.x, f0.y); a.i[1] = pkbf2(f0.z, f0.w);
        a.i[2] = pkbf2(f1.x, f1.y); a.i[3] = pkbf2(f1.z, f1.w);
        #pragma unroll
        for (int ct = 0; ct < 8; ++ct)
            acc[ct] = mfma_bf16(a.s, B1[(ks * 8 + ct) * 64 + lane], acc[ct]);
    }

    #pragma unroll
    for (int ct = 0; ct < 8; ++ct) {
        float bb = b1[ct * 16 + j0];
        #pragma unroll
        for (int rg = 0; rg < 4; ++rg) {
            int row = rt * 16 + hi * 4 + rg;
            float y = fmaxf(acc[ct][rg] + bb, 0.0f);
            int addr = (row * 256 + (ct * 16 + j0) * 2) ^ ((row & 7) << 4);
            *(__hip_bfloat16*)(hbuf + addr) = __float2bfloat16(y);
        }
    }
    asm volatile("" ::: "memory");

    // GEMM2 — reuse acc
    #pragma unroll
    for (int ct = 0; ct < 8; ++ct) acc[ct] = (f32x4){0.f, 0.f, 0.f, 0.f};
    {
        int arow = rt * 16 + j0;
        #pragma unroll
        for (int ks = 0; ks < 4; ++ks) {
            int addr = (arow * 256 + (ks * 32 + hi * 8) * 2) ^ ((arow & 7) << 4);
            frag_u a;
            a.i = *(const i32x4*)(hbuf + addr);
            #pragma unroll
            for (int ct = 0; ct < 8; ++ct)
                acc[ct] = mfma_bf16(a.s, B2[(ks * 8 + ct) * 64 + lane], acc[ct]);
        }
    }

    float b2v[8], gv[8], bv[8];
    #pragma unroll
    for (int ct = 0; ct < 8; ++ct) {
        int c = ct * 16 + j0;
        b2v[ct] = b2[c]; gv[ct] = g[c]; bv[ct] = beta[c];
    }
    #pragma unroll
    for (int rg = 0; rg < 4; ++rg) {
        int row = rt * 16 + hi * 4 + rg;
        long n = (long)blockIdx.x * 64 + row;
        float y[8]; float s = 0.f, sq = 0.f;
        #pragma unroll
        for (int ct = 0; ct < 8; ++ct) {
            y[ct] = acc[ct][rg] + b2v[ct];
            s += y[ct]; sq += y[ct] * y[ct];
        }
        #pragma unroll
        for (int m = 1; m <= 8; m <<= 1) { s += __shfl_xor(s, m); sq += __shfl_xor(sq, m); }
        float mu = s * (1.0f / 128.0f);
        float var = sq * (1.0f / 128.0f) - mu * mu;
        float rs = rsqrtf(var + LN_EPS);
        if (n < N_NODES) {
            const float* nfr = nf + (size_t)n * D;
            float* outr = out_nf + (size_t)n * D;
            #pragma unroll
            for (int ct = 0; ct < 8; ++ct) {
                int c = ct * 16 + j0;
                float o = (y[ct] - mu) * rs * gv[ct] + bv[ct];
                outr[c] = o + nfr[c];                        // + node residual
            }
        }
    }
}

extern "C" void kernel_launch(void* const* d_in, const int* in_sizes, int n_in,
                              void* d_out, int out_size, void* d_ws, size_t ws_size,
                              hipStream_t stream)
{
    (void)in_sizes; (void)n_in; (void)out_size;
    const float* nf    = (const float*)d_in[0];
    const float* ef    = (const float*)d_in[1];
    const int*   snd   = (const int*)d_in[2];
    const int*   rcv   = (const int*)d_in[3];
    const float* eW1   = (const float*)d_in[4];
    const float* eb1   = (const float*)d_in[5];
    const float* eW2   = (const float*)d_in[6];
    const float* eb2   = (const float*)d_in[7];
    const float* eg    = (const float*)d_in[8];
    const float* ebeta = (const float*)d_in[9];
    const float* nW1   = (const float*)d_in[10];
    const float* nb1   = (const float*)d_in[11];
    const float* nW2   = (const float*)d_in[12];
    const float* nb2   = (const float*)d_in[13];
    const float* ng    = (const float*)d_in[14];
    const float* nbeta = (const float*)d_in[15];
    const float* aW    = (const float*)d_in[16];
    const float* ab    = (const float*)d_in[17];

    float* out_nf = (float*)d_out;
    float* out_ef = out_nf + (size_t)N_NODES * D;
    char*  ws     = (char*)d_ws;

    const bool use_raw = (ws_size >= WS_NEED_RAW);   // constant per-harness -> deterministic

    k_init<<<196, 256, 0, stream>>>(eW1, eW2, nW1, nW2, ws);

    k_count<<<(N_EDGES + 255) / 256, 256, 0, stream>>>(rcv, (int*)(ws + DEG_OFF));
    k_scan<<<1, 256, 0, stream>>>((const int*)(ws + DEG_OFF), (int*)(ws + ROWPTR_OFF));
    k_fill<<<(N_EDGES + 255) / 256, 256, 0, stream>>>(
        rcv, (const int*)(ws + ROWPTR_OFF), (int*)(ws + CURSOR_OFF), (int*)(ws + ELIST_OFF));

    if (use_raw) {
        k_edge<1><<<N_EDGES / 64, 256, 0, stream>>>(
            nf, ef, snd, rcv,
            (const i32x4*)(ws + W1P_OFF), (const i32x4*)(ws + W2P_OFF),
            eb1, eb2, eg, ebeta, aW, ab,
            out_ef, (float*)(ws + LOGITS_OFF), (unsigned short*)(ws + RAW_OFF));
        k_agg<1><<<N_NODES / 4, 256, 0, stream>>>(
            (const int*)(ws + ROWPTR_OFF), (const int*)(ws + ELIST_OFF),
            (const float*)(ws + LOGITS_OFF), (const unsigned int*)(ws + RAW_OFF),
            nullptr, nullptr, (float*)(ws + AGG_OFF));
    } else {
        k_edge<0><<<N_EDGES / 64, 256, 0, stream>>>(
            nf, ef, snd, rcv,
            (const i32x4*)(ws + W1P_OFF), (const i32x4*)(ws + W2P_OFF),
            eb1, eb2, eg, ebeta, aW, ab,
            out_ef, (float*)(ws + LOGITS_OFF), nullptr);
        k_agg<0><<<N_NODES / 4, 256, 0, stream>>>(
            (const int*)(ws + ROWPTR_OFF), (const int*)(ws + ELIST_OFF),
            (const float*)(ws + LOGITS_OFF), nullptr,
            out_ef, ef, (float*)(ws + AGG_OFF));
    }

    k_node<<<(N_NODES + 63) / 64, 256, 0, stream>>>(
        nf, (const float*)(ws + AGG_OFF),
        (const s16x8*)(ws + NW1P_OFF), (const s16x8*)(ws + NW2P_OFF),
        nb1, nb2, ng, nbeta, out_nf);
}